// Round 7
// baseline (146.130 us; speedup 1.0000x reference)
//
#include <hip/hip_runtime.h>

typedef __attribute__((ext_vector_type(8))) short short8;
typedef __attribute__((ext_vector_type(8))) __bf16 bf16x8;
typedef __attribute__((ext_vector_type(4))) float f32x4;

// sizes
#define B_ 4
#define C_ 64
#define H_ 128
#define W_ 128
#define P_ (H_*W_)      // 16384
#define E_ 16
#define Kk 3

// ws layout (bytes)
#define OFF_XT   0u
#define XT_BYTES (4u*130u*130u*64u*2u)          // 8,652,800
#define OFF_A    8652800u
#define A_BYTES  (1024u*576u*2u)                 // 1,179,648
#define OFF_PARA 9832448u

__device__ inline unsigned short f2bf(float f) {
    union { float f; unsigned u; } v; v.f = f;
    unsigned r = v.u + 0x7FFF + ((v.u >> 16) & 1);
    return (unsigned short)(r >> 16);
}

// ---------- transpose+pad x (NCHW f32) -> xt[b][y+1][x+1][c] bf16 ----------
// Also zeroes the halo (left/right cols of its row; blocks y==0/127 zero the
// top/bottom padded rows) so the separate k_zero pass is gone.
__global__ __launch_bounds__(128) void k_transpose(const float* __restrict__ x,
                                                   unsigned short* __restrict__ xt) {
    int b = blockIdx.x >> 7, y = blockIdx.x & 127;
    int t = threadIdx.x; // x coordinate
    const float* src = x + (size_t)b * C_ * P_ + y * W_ + t;
    unsigned short* dst = xt + ((size_t)(b * 130 + y + 1) * 130 + t + 1) * 64;
#pragma unroll
    for (int i = 0; i < 8; ++i) {
        short8 v;
#pragma unroll
        for (int j = 0; j < 8; ++j) v[j] = (short)f2bf(src[(size_t)(i * 8 + j) * P_]);
        ((short8*)dst)[i] = v;
    }
    short8 z = {0,0,0,0,0,0,0,0};
    // left/right halo pixels (cols 0 and 129) of padded row y+1
    if (t < 16) {
        int col = (t >> 3) * 129, i = t & 7;
        unsigned short* bp = xt + ((size_t)(b * 130 + y + 1) * 130 + col) * 64;
        ((short8*)bp)[i] = z;
    }
    // top/bottom padded rows
    if (y == 0 || y == 127) {
        int prow = (y == 0) ? 0 : 129;
        unsigned short* rp = xt + (size_t)(b * 130 + prow) * 130 * 64;
        for (int ci = t; ci < 1040; ci += 128) ((short8*)rp)[ci] = z;
    }
}

// ---------- build A[row=o*16+e][col=(kh*3+kw)*64+c] bf16 from W ----------
__global__ __launch_bounds__(256) void k_prepA(const float* __restrict__ Wsrc,
                                               unsigned short* __restrict__ A) {
    __shared__ float lw[9216];
    int o = blockIdx.x, t = threadIdx.x;
    const float* src = Wsrc + (size_t)o * 9216; // 576*16 per o, layout [j=c*9+tap][e]
    for (int lin = t; lin < 9216; lin += 256) lw[lin] = src[lin];
    __syncthreads();
    unsigned short* dst = A + (size_t)o * 16 * 576;
    for (int lin = t; lin < 9216; lin += 256) {
        int e = lin / 576, col = lin - e * 576;
        int tap = col >> 6, c = col & 63;
        dst[e * 576 + col] = f2bf(lw[(c * 9 + tap) * 16 + e]);
    }
}

// ---------- fused predictor: conv1x1 + relu + conv3x3 -> para[b][e][p] ----------
// block = one image row (b,y), 128 threads (1 px each). Phase 1 computes r1
// for rows y-1..y+1 into LDS (halo recompute, +17 pad kills bank conflicts);
// phase 2 does the 3x3 conv from LDS. Exact f32 math as before.
__global__ __launch_bounds__(128) void k_pred(const float* __restrict__ x,
                                              const float* __restrict__ pw,
                                              const float* __restrict__ pb,
                                              const float* __restrict__ cw,
                                              const float* __restrict__ cb,
                                              float* __restrict__ para) {
    __shared__ float lpw[1024];
    __shared__ float lcw[2304];
    __shared__ float lpb[16], lcb[16];
    __shared__ float r1t[3][128][17];
    int t = threadIdx.x;
    int b = blockIdx.x >> 7, y = blockIdx.x & 127;
    for (int lin = t; lin < 1024; lin += 128) lpw[lin] = pw[lin];
    for (int lin = t; lin < 2304; lin += 128) lcw[lin] = cw[lin];
    if (t < 16) { lpb[t] = pb[t]; lcb[t] = cb[t]; }
    __syncthreads();

    // phase 1: r1 for 3 rows
    for (int rr = 0; rr < 3; ++rr) {
        int yy = y + rr - 1;
        if (yy >= 0 && yy <= 127) {
            const float* xs = x + (size_t)b * C_ * P_ + yy * 128 + t;
            float s[16];
#pragma unroll
            for (int e = 0; e < 16; ++e) s[e] = lpb[e];
            for (int c = 0; c < 64; ++c) {
                float xv = xs[(size_t)c * P_];
#pragma unroll
                for (int e = 0; e < 16; ++e) s[e] = fmaf(lpw[e * 64 + c], xv, s[e]);
            }
#pragma unroll
            for (int e = 0; e < 16; ++e) r1t[rr][t][e] = fmaxf(s[e], 0.f);
        } else {
#pragma unroll
            for (int e = 0; e < 16; ++e) r1t[rr][t][e] = 0.f;
        }
    }
    __syncthreads();

    // phase 2: 3x3 conv over r1t
    float s[16];
#pragma unroll
    for (int e = 0; e < 16; ++e) s[e] = lcb[e];
    for (int rr = 0; rr < 3; ++rr) {
        for (int dx = 0; dx < 3; ++dx) {
            int xx = t + dx - 1;
            if (xx < 0 || xx > 127) continue;
            int tap = rr * 3 + dx;
#pragma unroll
            for (int ep = 0; ep < 16; ++ep) {
                float v = r1t[rr][xx][ep];
#pragma unroll
                for (int e = 0; e < 16; ++e)
                    s[e] = fmaf(lcw[(e * 16 + ep) * 9 + tap], v, s[e]);
            }
        }
    }
    float* d = para + (size_t)b * 16 * P_ + y * 128 + t;
#pragma unroll
    for (int e = 0; e < 16; ++e) d[(size_t)e * P_] = s[e];
}

// ---------- main fused kernel ----------
// R6 skeleton: 512 threads (8 waves), 4 image rows x 16 o's, LDS 99,840 B
// (1 block/CU, 2 waves/SIMD), af prefetch, setprio. New in R7: anti-phase
// nudge -- ohalf=1 waves (the SIMD partners of ohalf=0 waves) sleep ~512cy
// after the barrier so SIMD-sharing waves run a half-step out of phase:
// one wave's MFMA burst covers the other's LDS-port phase (convoy break).
__global__ __launch_bounds__(512, 2) void k_main(const unsigned short* __restrict__ xt,
                                                 const unsigned short* __restrict__ A,
                                                 const float* __restrict__ para,
                                                 float* __restrict__ out) {
    __shared__ unsigned short lds[6 * 130 * 64]; // 99,840 B
    int r = blockIdx.x;
    int xcd = r & 7;
    int ord = r >> 3;
    int osl = ord & 3;          // o-slice: 16 o's
    int bygl = ord >> 2;        // [0,16)
    int byg = bygl * 8 + xcd;   // [0,128)
    int b = byg >> 5, yg = byg & 31;
    int y0 = yg * 4;            // first image row of this block

    int tid = threadIdx.x;
    int wave = tid >> 6, lane = tid & 63, lhi = lane >> 4, llo = lane & 15;
    int wrow = wave & 3, ohalf = wave >> 2;

    // stage 6 padded xt rows (y0 .. y0+5), swizzle byte ^= ((xx&7)<<4)
    const unsigned short* xrow = xt + (size_t)(b * 130 + y0) * 130 * 64;
    for (int ci = tid; ci < 6240; ci += 512) {
        int row = ci / 1040, rem = ci - row * 1040;
        int xx = rem >> 3, cc = rem & 7;
        short8 v = *(const short8*)(xrow + ((size_t)row * 130 + xx) * 64 + cc * 8);
        int lb = row * 16640 + xx * 128 + ((cc * 16) ^ ((xx & 7) << 4));
        *(short8*)((char*)lds + lb) = v;
    }
    __syncthreads();

    // convoy break: stagger SIMD-partner waves by ~one MFMA burst
    if (ohalf) __builtin_amdgcn_s_sleep(8);

    int y = y0 + wrow;
    const float* pp = para + (size_t)b * 16 * P_ + y * 128;
    float* po = out + (size_t)b * 64 * P_ + y * 128;

    // precomputed LDS read vaddrs: qv[parity][kw]; full addr = qv + kh*16640 + pg*2048
    int qv[2][3];
#pragma unroll
    for (int kw = 0; kw < 3; ++kw) {
        int rowi = llo + kw;
        int base0 = wrow * 16640 + rowi * 128 + ((lhi * 16) ^ ((rowi & 7) << 4));
        qv[0][kw] = base0;
        qv[1][kw] = base0 ^ 64;
    }
    const char* ldsc = (const char*)lds;

#pragma unroll 1
    for (int chunk = 0; chunk < 2; ++chunk) {
        int obase = osl * 16 + ohalf * 8 + chunk * 4;
        const unsigned short* Ab = A + (size_t)(obase * 16 + llo) * 576 + lhi * 8;

        f32x4 acc[4][8];
#pragma unroll
        for (int f = 0; f < 4; ++f)
#pragma unroll
            for (int pg = 0; pg < 8; ++pg) acc[f][pg] = (f32x4){0.f, 0.f, 0.f, 0.f};

        bf16x8 afA[4], afB[4];
        // prologue: A-frags for ks=0
#pragma unroll
        for (int f = 0; f < 4; ++f)
            afA[f] = *(const bf16x8*)(Ab + (size_t)f * 9216);

#pragma unroll 1
        for (int kh = 0; kh < 3; ++kh) {
#pragma unroll 1
            for (int kw = 0; kw < 3; ++kw) {
                const int ksc = kh * 6 + kw * 2; // current even ks
                const char* bprow = ldsc + kh * 16640;
                // ---- half 0 (parity 0): compute with afA, prefetch ksc+1 -> afB
                {
#pragma unroll
                    for (int f = 0; f < 4; ++f)
                        afB[f] = *(const bf16x8*)(Ab + (size_t)f * 9216 + (ksc + 1) * 32);
                    const char* bp = bprow + qv[0][kw];
                    bf16x8 bf[8];
#pragma unroll
                    for (int pg = 0; pg < 8; ++pg)
                        bf[pg] = *(const bf16x8*)(bp + pg * 2048);
                    __builtin_amdgcn_s_setprio(1);
#pragma unroll
                    for (int f = 0; f < 4; ++f)
#pragma unroll
                        for (int pg = 0; pg < 8; ++pg)
                            acc[f][pg] = __builtin_amdgcn_mfma_f32_16x16x32_bf16(afA[f], bf[pg], acc[f][pg], 0, 0, 0);
                    __builtin_amdgcn_s_setprio(0);
                }
                // ---- half 1 (parity 1): compute with afB, prefetch ksc+2 -> afA
                {
                    // ksc+2==18 at the very end reads 48B past this chunk's A
                    // slice (still inside ws) -- harmless, overwritten next chunk.
#pragma unroll
                    for (int f = 0; f < 4; ++f)
                        afA[f] = *(const bf16x8*)(Ab + (size_t)f * 9216 + (ksc + 2) * 32);
                    const char* bp = bprow + qv[1][kw];
                    bf16x8 bf[8];
#pragma unroll
                    for (int pg = 0; pg < 8; ++pg)
                        bf[pg] = *(const bf16x8*)(bp + pg * 2048);
                    __builtin_amdgcn_s_setprio(1);
#pragma unroll
                    for (int f = 0; f < 4; ++f)
#pragma unroll
                        for (int pg = 0; pg < 8; ++pg)
                            acc[f][pg] = __builtin_amdgcn_mfma_f32_16x16x32_bf16(afB[f], bf[pg], acc[f][pg], 0, 0, 0);
                    __builtin_amdgcn_s_setprio(0);
                }
            }
        }

        // epilogue: multiply rows (e) by para[e,p], reduce over e
        float pvv[8][4];
#pragma unroll
        for (int pg = 0; pg < 8; ++pg)
#pragma unroll
            for (int rr = 0; rr < 4; ++rr)
                pvv[pg][rr] = pp[(size_t)(lhi * 4 + rr) * P_ + pg * 16 + llo];

#pragma unroll
        for (int f = 0; f < 4; ++f) {
            int o = obase + f;
#pragma unroll
            for (int pg = 0; pg < 8; ++pg) {
                float s = acc[f][pg][0] * pvv[pg][0] + acc[f][pg][1] * pvv[pg][1] +
                          acc[f][pg][2] * pvv[pg][2] + acc[f][pg][3] * pvv[pg][3];
                s += __shfl_xor(s, 16);
                s += __shfl_xor(s, 32);
                if (lhi == 0)
                    __builtin_nontemporal_store(s, &po[(size_t)o * P_ + pg * 16 + llo]);
            }
        }
    }
}

extern "C" void kernel_launch(void* const* d_in, const int* in_sizes, int n_in,
                              void* d_out, int out_size, void* d_ws, size_t ws_size,
                              hipStream_t stream) {
    const float* x  = (const float*)d_in[0];
    const float* W  = (const float*)d_in[1];
    const float* pw = (const float*)d_in[2];
    const float* pb = (const float*)d_in[3];
    const float* cw = (const float*)d_in[4];
    const float* cb = (const float*)d_in[5];
    float* out = (float*)d_out;
    char* ws = (char*)d_ws;
    unsigned short* xt = (unsigned short*)(ws + OFF_XT);
    unsigned short* Am = (unsigned short*)(ws + OFF_A);
    float* para = (float*)(ws + OFF_PARA);

    hipLaunchKernelGGL(k_transpose, dim3(B_ * H_), dim3(128), 0, stream, x, xt);
    hipLaunchKernelGGL(k_prepA, dim3(64), dim3(256), 0, stream, W, Am);
    hipLaunchKernelGGL(k_pred, dim3(B_ * H_), dim3(128), 0, stream, x, pw, pb, cw, cb, para);
    hipLaunchKernelGGL(k_main, dim3(512), dim3(512), 0, stream, xt, Am, para, out);
}